// Round 1
// baseline (1836.578 us; speedup 1.0000x reference)
//
#include <hip/hip_runtime.h>
#include <hip/hip_bf16.h>

#define B_ 1024
#define D_ 256
#define Q_ 131072
#define K_ 200
#define C_ 1000
#define INV_T 14.285714285714286f
#define EPS_ 1e-5f
#define CAP 2048

#define GBM 128
#define GBN 128
#define GBK 16
#define LDS_STRIDE (GBM + 4)

__device__ __forceinline__ unsigned key_of(float v) {
    unsigned u = __float_as_uint(v);
    return (u & 0x80000000u) ? ~u : (u | 0x80000000u);
}

// ---------------------------------------------------------------- normalize
__global__ __launch_bounds__(256) void norm_kernel(const float* __restrict__ x,
                                                   float* __restrict__ xn) {
    int row = blockIdx.x;
    int tid = threadIdx.x;
    float v = x[row * D_ + tid];
    float s = v * v;
#pragma unroll
    for (int off = 32; off > 0; off >>= 1) s += __shfl_xor(s, off);
    __shared__ float wsum[4];
    int lane = tid & 63, wid = tid >> 6;
    if (lane == 0) wsum[wid] = s;
    __syncthreads();
    float tot = wsum[0] + wsum[1] + wsum[2] + wsum[3];
    xn[row * D_ + tid] = v / sqrtf(tot);
}

// ---------------------------------------------------------------- fp32 GEMM: dist = xn @ memory^T
// tile 128x128, 256 threads, 8x8 per thread, k-major LDS
__global__ __launch_bounds__(256) void gemm_kernel(const float* __restrict__ A,
                                                   const float* __restrict__ M,
                                                   float* __restrict__ dist,
                                                   int row0) {
    __shared__ float As[GBK][LDS_STRIDE];
    __shared__ float Bs[GBK][LDS_STRIDE];
    const int tid = threadIdx.x;
    const int tx = tid & 15;
    const int ty = tid >> 4;
    const long long qbase = (long long)blockIdx.x * GBN;
    const int arow = row0 + blockIdx.y * GBM;

    const int lr = tid >> 1;       // 0..127
    const int lk = (tid & 1) * 8;  // 0 or 8

    const float* Aptr = A + (long long)(arow + lr) * D_ + lk;
    const float* Mptr = M + (qbase + lr) * D_ + lk;

    float acc[8][8];
#pragma unroll
    for (int i = 0; i < 8; ++i)
#pragma unroll
        for (int j = 0; j < 8; ++j) acc[i][j] = 0.f;

    for (int kk = 0; kk < D_; kk += GBK) {
        float4 a0 = *(const float4*)(Aptr + kk);
        float4 a1 = *(const float4*)(Aptr + kk + 4);
        float4 b0 = *(const float4*)(Mptr + kk);
        float4 b1 = *(const float4*)(Mptr + kk + 4);
        As[lk + 0][lr] = a0.x; As[lk + 1][lr] = a0.y;
        As[lk + 2][lr] = a0.z; As[lk + 3][lr] = a0.w;
        As[lk + 4][lr] = a1.x; As[lk + 5][lr] = a1.y;
        As[lk + 6][lr] = a1.z; As[lk + 7][lr] = a1.w;
        Bs[lk + 0][lr] = b0.x; Bs[lk + 1][lr] = b0.y;
        Bs[lk + 2][lr] = b0.z; Bs[lk + 3][lr] = b0.w;
        Bs[lk + 4][lr] = b1.x; Bs[lk + 5][lr] = b1.y;
        Bs[lk + 6][lr] = b1.z; Bs[lk + 7][lr] = b1.w;
        __syncthreads();
#pragma unroll
        for (int k = 0; k < GBK; ++k) {
            float a[8], b[8];
            *(float4*)&a[0] = *(const float4*)&As[k][ty * 8];
            *(float4*)&a[4] = *(const float4*)&As[k][ty * 8 + 4];
            *(float4*)&b[0] = *(const float4*)&Bs[k][tx * 8];
            *(float4*)&b[4] = *(const float4*)&Bs[k][tx * 8 + 4];
#pragma unroll
            for (int i = 0; i < 8; ++i)
#pragma unroll
                for (int j = 0; j < 8; ++j) acc[i][j] = fmaf(a[i], b[j], acc[i][j]);
        }
        __syncthreads();
    }

    const int lrow0 = blockIdx.y * GBM + ty * 8;
    float* dbase = dist + (long long)lrow0 * Q_ + qbase + tx * 8;
#pragma unroll
    for (int i = 0; i < 8; ++i) {
        float4 w0 = make_float4(acc[i][0], acc[i][1], acc[i][2], acc[i][3]);
        float4 w1 = make_float4(acc[i][4], acc[i][5], acc[i][6], acc[i][7]);
        *(float4*)(dbase + (long long)i * Q_) = w0;
        *(float4*)(dbase + (long long)i * Q_ + 4) = w1;
    }
}

// ---------------------------------------------------------------- per-row top-K + softmax + scatter
// one block (256 threads) per row; exact-K via histogram threshold + candidate rank-count
__global__ __launch_bounds__(256) void select_kernel(const float* __restrict__ dist,
                                                     const int* __restrict__ labels,
                                                     float* __restrict__ out,
                                                     int row0) {
    __shared__ unsigned hist[4096];   // reused as candidate storage after threshold
    __shared__ unsigned seg[256];
    __shared__ float bins[C_];
    __shared__ unsigned sh_bstar, sh_cnt, sh_tie, sh_tkey;
    __shared__ int sh_gstar;

    float* cand_val = (float*)hist;              // [0 .. CAP)
    unsigned* cand_idx = (unsigned*)(hist + CAP);  // [CAP .. 2*CAP)
    float* segf = (float*)seg;

    const int tid = threadIdx.x;
    const int lrow = blockIdx.x;
    const float* drow = dist + (long long)lrow * Q_;

    for (int i = tid; i < 4096; i += 256) hist[i] = 0u;
    __syncthreads();

    // phase 1: histogram of top-12 bits of monotonic key
    for (int i = tid; i < Q_; i += 256) {
        unsigned kk = key_of(drow[i]);
        atomicAdd(&hist[kk >> 20], 1u);
    }
    __syncthreads();

    // phase 2: find threshold bin (count from top until >= K)
    unsigned s = 0;
#pragma unroll
    for (int j = 0; j < 16; ++j) s += hist[tid * 16 + j];
    seg[tid] = s;
    __syncthreads();
    if (tid == 0) {
        unsigned cum = 0; int bstar = 0;
        for (int sg = 255; sg >= 0; --sg) {
            if (cum + seg[sg] >= (unsigned)K_) {
                for (int b = sg * 16 + 15; ; --b) {
                    cum += hist[b];
                    if (cum >= (unsigned)K_) { bstar = b; break; }
                }
                break;
            }
            cum += seg[sg];
        }
        sh_bstar = (unsigned)bstar;
        sh_cnt = 0u;
    }
    __syncthreads();
    const unsigned bst = sh_bstar;

    // phase 3: compact candidates (key-bin >= bstar) into LDS (reuses hist storage)
    for (int i = tid; i < Q_; i += 256) {
        float v = drow[i];
        if ((key_of(v) >> 20) >= bst) {
            unsigned p = atomicAdd(&sh_cnt, 1u);
            if (p < CAP) { cand_val[p] = v; cand_idx[p] = (unsigned)i; }
        }
    }
    __syncthreads();
    const int n = (sh_cnt < (unsigned)CAP) ? (int)sh_cnt : CAP;

    // phase 4: row max
    float lm = -3.4e38f;
    for (int i = tid; i < n; i += 256) lm = fmaxf(lm, cand_val[i]);
    segf[tid] = lm;
    __syncthreads();
    for (int off = 128; off > 0; off >>= 1) {
        if (tid < off) segf[tid] = fmaxf(segf[tid], segf[tid + off]);
        __syncthreads();
    }
    const float m = segf[0];
    __syncthreads();

    // phase 5: exact Kth-largest key among candidates (rank counting)
    for (int i = tid; i < n; i += 256) {
        unsigned ki = key_of(cand_val[i]);
        int g = 0, eq = 0;
        for (int j = 0; j < n; ++j) {
            unsigned kj = key_of(cand_val[j]);
            g += (kj > ki);
            eq += (kj == ki);
        }
        if (g < K_ && g + eq >= K_) { sh_tkey = ki; sh_gstar = g; }
    }
    if (tid == 0) sh_tie = 0u;
    for (int c = tid; c < C_; c += 256) bins[c] = 0.f;
    __syncthreads();

    // phase 6: softmax numerators over exactly K included candidates
    const unsigned tkey = sh_tkey;
    const int rem = K_ - sh_gstar;
    float part = 0.f;
    for (int i = tid; i < n; i += 256) {
        float v = cand_val[i];
        unsigned ki = key_of(v);
        float e = 0.f;
        if (ki > tkey) e = __expf((v - m) * INV_T);
        else if (ki == tkey) {
            if (atomicAdd(&sh_tie, 1u) < (unsigned)rem) e = __expf((v - m) * INV_T);
        }
        cand_val[i] = e;  // own slot only; safe after phase-5 sync
        part += e;
    }
    segf[tid] = part;
    __syncthreads();
    for (int off = 128; off > 0; off >>= 1) {
        if (tid < off) segf[tid] += segf[tid + off];
        __syncthreads();
    }
    const float invS = 1.f / segf[0];

    // phase 7: scatter weights by label into LDS bins
    for (int i = tid; i < n; i += 256) {
        float e = cand_val[i];
        if (e > 0.f) {
            int lbl = labels[cand_idx[i]];
            if ((unsigned)lbl < (unsigned)C_) atomicAdd(&bins[lbl], e);
        }
    }
    __syncthreads();

    // phase 8: write final row: min(w + eps, 1)
    const long long obase = (long long)(row0 + lrow) * C_;
    for (int c = tid; c < C_; c += 256)
        out[obase + c] = fminf(bins[c] * invS + EPS_, 1.0f);
}

// ---------------------------------------------------------------- launch
extern "C" void kernel_launch(void* const* d_in, const int* in_sizes, int n_in,
                              void* d_out, int out_size, void* d_ws, size_t ws_size,
                              hipStream_t stream) {
    const float* x = (const float*)d_in[0];
    const float* mem = (const float*)d_in[1];
    const int* lab = (const int*)d_in[2];
    float* out = (float*)d_out;

    float* xn = (float*)d_ws;
    float* dist = xn + (size_t)B_ * D_;
    size_t fixed = (size_t)B_ * D_ * sizeof(float);
    size_t avail = (ws_size > fixed) ? ws_size - fixed : 0;

    int R = 1024;  // rows per chunk; shrink until dist chunk fits in workspace
    while (R > 128 && (size_t)R * Q_ * sizeof(float) > avail) R >>= 1;

    norm_kernel<<<B_, 256, 0, stream>>>(x, xn);
    for (int r0 = 0; r0 < B_; r0 += R) {
        dim3 g(Q_ / GBN, R / GBM);
        gemm_kernel<<<g, 256, 0, stream>>>(xn, mem, dist, r0);
        select_kernel<<<R, 256, 0, stream>>>(dist, lab, out, r0);
    }
}

// Round 2
// 1282.108 us; speedup vs baseline: 1.4325x; 1.4325x over previous
//
#include <hip/hip_runtime.h>
#include <hip/hip_bf16.h>

#define B_ 1024
#define D_ 256
#define Q_ 131072
#define K_ 200
#define C_ 1000
#define INV_T 14.285714285714286f
#define EPS_ 1e-5f
#define CAP 2048
#define SEGS 16
#define SEGSZ (Q_ / SEGS)

#define GBM 128
#define GBN 128
#define GBK 16
#define LDS_STRIDE (GBM + 4)

__device__ __forceinline__ unsigned key_of(float v) {
    unsigned u = __float_as_uint(v);
    return (u & 0x80000000u) ? ~u : (u | 0x80000000u);
}

// ---------------------------------------------------------------- normalize
__global__ __launch_bounds__(256) void norm_kernel(const float* __restrict__ x,
                                                   float* __restrict__ xn) {
    int row = blockIdx.x;
    int tid = threadIdx.x;
    float v = x[row * D_ + tid];
    float s = v * v;
#pragma unroll
    for (int off = 32; off > 0; off >>= 1) s += __shfl_xor(s, off);
    __shared__ float wsum[4];
    int lane = tid & 63, wid = tid >> 6;
    if (lane == 0) wsum[wid] = s;
    __syncthreads();
    float tot = wsum[0] + wsum[1] + wsum[2] + wsum[3];
    xn[row * D_ + tid] = v / sqrtf(tot);
}

// ---------------------------------------------------------------- fp32 GEMM: dist = xn @ memory^T
__global__ __launch_bounds__(256) void gemm_kernel(const float* __restrict__ A,
                                                   const float* __restrict__ M,
                                                   float* __restrict__ dist,
                                                   int row0) {
    __shared__ float As[GBK][LDS_STRIDE];
    __shared__ float Bs[GBK][LDS_STRIDE];
    const int tid = threadIdx.x;
    const int tx = tid & 15;
    const int ty = tid >> 4;
    const long long qbase = (long long)blockIdx.x * GBN;
    const int arow = row0 + blockIdx.y * GBM;

    const int lr = tid >> 1;
    const int lk = (tid & 1) * 8;

    const float* Aptr = A + (long long)(arow + lr) * D_ + lk;
    const float* Mptr = M + (qbase + lr) * D_ + lk;

    float acc[8][8];
#pragma unroll
    for (int i = 0; i < 8; ++i)
#pragma unroll
        for (int j = 0; j < 8; ++j) acc[i][j] = 0.f;

    for (int kk = 0; kk < D_; kk += GBK) {
        float4 a0 = *(const float4*)(Aptr + kk);
        float4 a1 = *(const float4*)(Aptr + kk + 4);
        float4 b0 = *(const float4*)(Mptr + kk);
        float4 b1 = *(const float4*)(Mptr + kk + 4);
        As[lk + 0][lr] = a0.x; As[lk + 1][lr] = a0.y;
        As[lk + 2][lr] = a0.z; As[lk + 3][lr] = a0.w;
        As[lk + 4][lr] = a1.x; As[lk + 5][lr] = a1.y;
        As[lk + 6][lr] = a1.z; As[lk + 7][lr] = a1.w;
        Bs[lk + 0][lr] = b0.x; Bs[lk + 1][lr] = b0.y;
        Bs[lk + 2][lr] = b0.z; Bs[lk + 3][lr] = b0.w;
        Bs[lk + 4][lr] = b1.x; Bs[lk + 5][lr] = b1.y;
        Bs[lk + 6][lr] = b1.z; Bs[lk + 7][lr] = b1.w;
        __syncthreads();
#pragma unroll
        for (int k = 0; k < GBK; ++k) {
            float a[8], b[8];
            *(float4*)&a[0] = *(const float4*)&As[k][ty * 8];
            *(float4*)&a[4] = *(const float4*)&As[k][ty * 8 + 4];
            *(float4*)&b[0] = *(const float4*)&Bs[k][tx * 8];
            *(float4*)&b[4] = *(const float4*)&Bs[k][tx * 8 + 4];
#pragma unroll
            for (int i = 0; i < 8; ++i)
#pragma unroll
                for (int j = 0; j < 8; ++j) acc[i][j] = fmaf(a[i], b[j], acc[i][j]);
        }
        __syncthreads();
    }

    const int lrow0 = blockIdx.y * GBM + ty * 8;
    float* dbase = dist + (long long)lrow0 * Q_ + qbase + tx * 8;
#pragma unroll
    for (int i = 0; i < 8; ++i) {
        float4 w0 = make_float4(acc[i][0], acc[i][1], acc[i][2], acc[i][3]);
        float4 w1 = make_float4(acc[i][4], acc[i][5], acc[i][6], acc[i][7]);
        *(float4*)(dbase + (long long)i * Q_) = w0;
        *(float4*)(dbase + (long long)i * Q_ + 4) = w1;
    }
}

// ---------------------------------------------------------------- zero scratch (ghist + cnt)
__global__ __launch_bounds__(256) void zero_kernel(unsigned* __restrict__ p, int n) {
    int i = blockIdx.x * 256 + threadIdx.x;
    if (i < n) p[i] = 0u;
}

// ---------------------------------------------------------------- per-(row,seg) histogram
__global__ __launch_bounds__(256) void hist_kernel(const float* __restrict__ dist,
                                                   unsigned* __restrict__ ghist) {
    __shared__ unsigned hist[4096];
    const int tid = threadIdx.x;
    const int row = blockIdx.x, seg = blockIdx.y;
    for (int i = tid; i < 4096; i += 256) hist[i] = 0u;
    __syncthreads();
    const float4* p = (const float4*)(dist + (long long)row * Q_ + (long long)seg * SEGSZ);
    for (int i = tid; i < SEGSZ / 4; i += 256) {
        float4 v = p[i];
        atomicAdd(&hist[key_of(v.x) >> 20], 1u);
        atomicAdd(&hist[key_of(v.y) >> 20], 1u);
        atomicAdd(&hist[key_of(v.z) >> 20], 1u);
        atomicAdd(&hist[key_of(v.w) >> 20], 1u);
    }
    __syncthreads();
    unsigned* gh = ghist + (long long)row * 4096;
    for (int i = tid; i < 4096; i += 256) {
        unsigned c = hist[i];
        if (c) atomicAdd(&gh[i], c);
    }
}

// ---------------------------------------------------------------- per-row threshold bin
__global__ __launch_bounds__(256) void thresh_kernel(const unsigned* __restrict__ ghist,
                                                     unsigned* __restrict__ thr) {
    __shared__ unsigned seg[256];
    __shared__ unsigned hloc[4096];
    const int tid = threadIdx.x;
    const unsigned* gh = ghist + (long long)blockIdx.x * 4096;
    unsigned s = 0;
    for (int j = 0; j < 16; ++j) {
        unsigned c = gh[tid * 16 + j];
        hloc[tid * 16 + j] = c;
        s += c;
    }
    seg[tid] = s;
    __syncthreads();
    if (tid == 0) {
        unsigned cum = 0; int bstar = 0;
        for (int sg = 255; sg >= 0; --sg) {
            if (cum + seg[sg] >= (unsigned)K_) {
                for (int b = sg * 16 + 15; ; --b) {
                    cum += hloc[b];
                    if (cum >= (unsigned)K_) { bstar = b; break; }
                }
                break;
            }
            cum += seg[sg];
        }
        thr[blockIdx.x] = (unsigned)bstar;
    }
}

// ---------------------------------------------------------------- per-(row,seg) filter+compact
__global__ __launch_bounds__(256) void filter_kernel(const float* __restrict__ dist,
                                                     const unsigned* __restrict__ thr,
                                                     unsigned* __restrict__ cnt,
                                                     float* __restrict__ candv,
                                                     unsigned* __restrict__ candi) {
    const int tid = threadIdx.x;
    const int row = blockIdx.x, seg = blockIdx.y;
    const unsigned bst = thr[row];
    const float4* p = (const float4*)(dist + (long long)row * Q_ + (long long)seg * SEGSZ);
    float* cv = candv + (long long)row * CAP;
    unsigned* ci = candi + (long long)row * CAP;
    const unsigned ibase = (unsigned)(seg * SEGSZ);
    for (int i = tid; i < SEGSZ / 4; i += 256) {
        float4 v = p[i];
        float a[4] = {v.x, v.y, v.z, v.w};
#pragma unroll
        for (int j = 0; j < 4; ++j) {
            if ((key_of(a[j]) >> 20) >= bst) {
                unsigned pidx = atomicAdd(&cnt[row], 1u);
                if (pidx < CAP) { cv[pidx] = a[j]; ci[pidx] = ibase + (unsigned)i * 4u + (unsigned)j; }
            }
        }
    }
}

// ---------------------------------------------------------------- per-row exact-K softmax + scatter
__global__ __launch_bounds__(256) void final_kernel(const unsigned* __restrict__ cnt,
                                                    const float* __restrict__ candv,
                                                    const unsigned* __restrict__ candi,
                                                    const int* __restrict__ labels,
                                                    float* __restrict__ out, int row0) {
    __shared__ float cval[CAP];
    __shared__ unsigned cidx[CAP];
    __shared__ float bins[C_];
    __shared__ float segf[256];
    __shared__ unsigned sh_tie, sh_tkey;
    __shared__ int sh_gstar;
    const int tid = threadIdx.x;
    const int row = blockIdx.x;
    unsigned c = cnt[row];
    const int n = (c < (unsigned)CAP) ? (int)c : CAP;
    for (int i = tid; i < n; i += 256) {
        cval[i] = candv[(long long)row * CAP + i];
        cidx[i] = candi[(long long)row * CAP + i];
    }
    for (int i = tid; i < C_; i += 256) bins[i] = 0.f;
    if (tid == 0) sh_tie = 0u;
    __syncthreads();

    // row max
    float lm = -3.4e38f;
    for (int i = tid; i < n; i += 256) lm = fmaxf(lm, cval[i]);
    segf[tid] = lm;
    __syncthreads();
    for (int off = 128; off > 0; off >>= 1) {
        if (tid < off) segf[tid] = fmaxf(segf[tid], segf[tid + off]);
        __syncthreads();
    }
    const float m = segf[0];
    __syncthreads();

    // exact Kth-largest key (rank counting)
    for (int i = tid; i < n; i += 256) {
        unsigned ki = key_of(cval[i]);
        int g = 0, eq = 0;
        for (int j = 0; j < n; ++j) {
            unsigned kj = key_of(cval[j]);
            g += (kj > ki);
            eq += (kj == ki);
        }
        if (g < K_ && g + eq >= K_) { sh_tkey = ki; sh_gstar = g; }
    }
    __syncthreads();

    const unsigned tkey = sh_tkey;
    const int rem = K_ - sh_gstar;
    float part = 0.f;
    for (int i = tid; i < n; i += 256) {
        float v = cval[i];
        unsigned ki = key_of(v);
        float e = 0.f;
        if (ki > tkey) e = __expf((v - m) * INV_T);
        else if (ki == tkey) {
            if (atomicAdd(&sh_tie, 1u) < (unsigned)rem) e = __expf((v - m) * INV_T);
        }
        cval[i] = e;  // own slot only
        part += e;
    }
    segf[tid] = part;
    __syncthreads();
    for (int off = 128; off > 0; off >>= 1) {
        if (tid < off) segf[tid] += segf[tid + off];
        __syncthreads();
    }
    const float invS = 1.f / segf[0];

    for (int i = tid; i < n; i += 256) {
        float e = cval[i];
        if (e > 0.f) {
            int lbl = labels[cidx[i]];
            if ((unsigned)lbl < (unsigned)C_) atomicAdd(&bins[lbl], e);
        }
    }
    __syncthreads();

    const long long ob = (long long)(row0 + row) * C_;
    for (int i = tid; i < C_; i += 256)
        out[ob + i] = fminf(bins[i] * invS + EPS_, 1.0f);
}

// ---------------------------------------------------------------- launch
extern "C" void kernel_launch(void* const* d_in, const int* in_sizes, int n_in,
                              void* d_out, int out_size, void* d_ws, size_t ws_size,
                              hipStream_t stream) {
    const float* x = (const float*)d_in[0];
    const float* mem = (const float*)d_in[1];
    const int* lab = (const int*)d_in[2];
    float* out = (float*)d_out;

    float* xn = (float*)d_ws;
    const size_t fixed = (size_t)B_ * D_ * sizeof(float);
    // per-row scratch: dist + ghist + cnt + thr + candv + candi
    const size_t per_row = (size_t)Q_ * 4 + 4096 * 4 + 4 + 4 + (size_t)CAP * 8;

    int R = 1024;
    while (R > 32 && fixed + (size_t)R * per_row > ws_size) R >>= 1;

    float* dist = xn + (size_t)B_ * D_;
    unsigned* ghist = (unsigned*)(dist + (size_t)R * Q_);
    unsigned* cnt = ghist + (size_t)R * 4096;
    unsigned* thr = cnt + R;
    float* candv = (float*)(thr + R);
    unsigned* candi = (unsigned*)(candv + (size_t)R * CAP);

    const int zero_n = R * 4096 + R;  // ghist + cnt (contiguous)

    norm_kernel<<<B_, 256, 0, stream>>>(x, xn);
    for (int r0 = 0; r0 < B_; r0 += R) {
        dim3 g(Q_ / GBN, R / GBM);
        gemm_kernel<<<g, 256, 0, stream>>>(xn, mem, dist, r0);
        zero_kernel<<<(zero_n + 255) / 256, 256, 0, stream>>>(ghist, zero_n);
        dim3 hs(R, SEGS);
        hist_kernel<<<hs, 256, 0, stream>>>(dist, ghist);
        thresh_kernel<<<R, 256, 0, stream>>>(ghist, thr);
        filter_kernel<<<hs, 256, 0, stream>>>(dist, thr, cnt, candv, candi);
        final_kernel<<<R, 256, 0, stream>>>(cnt, candv, candi, lab, out, r0);
    }
}

// Round 3
// 857.629 us; speedup vs baseline: 2.1415x; 1.4949x over previous
//
#include <hip/hip_runtime.h>
#include <hip/hip_bf16.h>

#define B_ 1024
#define D_ 256
#define Q_ 131072
#define K_ 200
#define C_ 1000
#define INV_T 14.285714285714286f
#define EPS_ 1e-5f
#define CAP 2048
#define SEGS 16
#define SEGSZ (Q_ / SEGS)

// fp32 fallback GEMM tile
#define GBM 128
#define GBN 128
#define GBK 16
#define LDS_STRIDE (GBM + 4)

// MFMA GEMM tile
#define TBM 128
#define TBN 128
#define TBK 64   // bf16 elems per k-step

typedef __attribute__((ext_vector_type(8))) short bf16x8;
typedef __attribute__((ext_vector_type(4))) float f32x4;

__device__ __forceinline__ unsigned key_of(float v) {
    unsigned u = __float_as_uint(v);
    return (u & 0x80000000u) ? ~u : (u | 0x80000000u);
}

__device__ __forceinline__ unsigned short f2bf(float f) {  // RNE, inputs are finite
    unsigned u = __float_as_uint(f);
    unsigned r = (u + 0x7FFFu + ((u >> 16) & 1u)) >> 16;
    return (unsigned short)r;
}
__device__ __forceinline__ float bf2f(unsigned short h) {
    return __uint_as_float((unsigned)h << 16);
}

__device__ __forceinline__ void gl_lds16(const void* g, void* l) {
    __builtin_amdgcn_global_load_lds(
        (const __attribute__((address_space(1))) unsigned*)g,
        (__attribute__((address_space(3))) unsigned*)l, 16, 0, 0);
}

// ---------------------------------------------------------------- normalize (fallback path)
__global__ __launch_bounds__(256) void norm_kernel(const float* __restrict__ x,
                                                   float* __restrict__ xn) {
    int row = blockIdx.x;
    int tid = threadIdx.x;
    float v = x[row * D_ + tid];
    float s = v * v;
#pragma unroll
    for (int off = 32; off > 0; off >>= 1) s += __shfl_xor(s, off);
    __shared__ float wsum[4];
    int lane = tid & 63, wid = tid >> 6;
    if (lane == 0) wsum[wid] = s;
    __syncthreads();
    float tot = wsum[0] + wsum[1] + wsum[2] + wsum[3];
    xn[row * D_ + tid] = v / sqrtf(tot);
}

// ---------------------------------------------------------------- normalize + bf16 hi/lo split
__global__ __launch_bounds__(256) void normsplit_kernel(const float* __restrict__ x,
                                                        unsigned short* __restrict__ ahi,
                                                        unsigned short* __restrict__ alo) {
    int row = blockIdx.x;
    int tid = threadIdx.x;
    float v = x[row * D_ + tid];
    float s = v * v;
#pragma unroll
    for (int off = 32; off > 0; off >>= 1) s += __shfl_xor(s, off);
    __shared__ float wsum[4];
    int lane = tid & 63, wid = tid >> 6;
    if (lane == 0) wsum[wid] = s;
    __syncthreads();
    float tot = wsum[0] + wsum[1] + wsum[2] + wsum[3];
    float xv = v / sqrtf(tot);
    unsigned short h = f2bf(xv);
    ahi[row * D_ + tid] = h;
    alo[row * D_ + tid] = f2bf(xv - bf2f(h));
}

// ---------------------------------------------------------------- memory -> bf16 hi/lo split
__global__ __launch_bounds__(256) void convB_kernel(const float* __restrict__ m,
                                                    unsigned short* __restrict__ bhi,
                                                    unsigned short* __restrict__ blo) {
    size_t i = (size_t)blockIdx.x * 256 + threadIdx.x;
    const size_t stride = (size_t)gridDim.x * 256;
    const size_t n4 = (size_t)Q_ * D_ / 4;
    for (; i < n4; i += stride) {
        float4 v = ((const float4*)m)[i];
        ushort4 h, l;
        h.x = f2bf(v.x); l.x = f2bf(v.x - bf2f(h.x));
        h.y = f2bf(v.y); l.y = f2bf(v.y - bf2f(h.y));
        h.z = f2bf(v.z); l.z = f2bf(v.z - bf2f(h.z));
        h.w = f2bf(v.w); l.w = f2bf(v.w - bf2f(h.w));
        ((ushort4*)bhi)[i] = h;
        ((ushort4*)blo)[i] = l;
    }
}

// ---------------------------------------------------------------- MFMA GEMM: dist = [Ahi|Ahi|Alo] @ [Bhi|Blo|Bhi]^T
// 128x128 tile, BK=64, 4 waves x (64x64), mfma 16x16x32 bf16, gload_lds16 + XOR swizzle
__global__ __launch_bounds__(256) void mfma_gemm(const unsigned short* __restrict__ Ahi,
                                                 const unsigned short* __restrict__ Alo,
                                                 const unsigned short* __restrict__ Bhi,
                                                 const unsigned short* __restrict__ Blo,
                                                 float* __restrict__ dist, int row0) {
    __shared__ alignas(16) unsigned short Asm[TBM * TBK];
    __shared__ alignas(16) unsigned short Bsm[TBN * TBK];
    const int tid = threadIdx.x;
    const int lane = tid & 63, wave = tid >> 6;
    const int wr = wave >> 1, wc = wave & 1;
    const int l15 = lane & 15, kb = lane >> 4;
    const int arow0 = row0 + blockIdx.y * TBM;     // absolute row into Ahi/Alo
    const long long qbase = (long long)blockIdx.x * TBN;

    // staging geometry (per-thread invariant): linear LDS dest, inverse-swizzled source
    int srow[4], soff[4], ldso[4];
#pragma unroll
    for (int i = 0; i < 4; ++i) {
        int idx = i * 256 + tid;
        srow[i] = idx >> 3;
        int sp = idx & 7;
        soff[i] = (sp ^ (srow[i] & 7)) * 8;  // logical k-slot source offset (elems)
        ldso[i] = idx * 8;                   // linear LDS elem offset
    }

    f32x4 zero4 = {0.f, 0.f, 0.f, 0.f};
    f32x4 acc[4][4];
#pragma unroll
    for (int m = 0; m < 4; ++m)
#pragma unroll
        for (int n = 0; n < 4; ++n) acc[m][n] = zero4;

    for (int t = 0; t < 12; ++t) {
        const int region = t >> 2;
        const int kk = (t & 3) * TBK;
        const unsigned short* Asrc = (region == 2) ? Alo : Ahi;
        const unsigned short* Bsrc = (region == 1) ? Blo : Bhi;
#pragma unroll
        for (int i = 0; i < 4; ++i)
            gl_lds16(Asrc + (long long)(arow0 + srow[i]) * D_ + kk + soff[i], &Asm[ldso[i]]);
#pragma unroll
        for (int i = 0; i < 4; ++i)
            gl_lds16(Bsrc + (qbase + srow[i]) * D_ + kk + soff[i], &Bsm[ldso[i]]);
        __syncthreads();

        bf16x8 afr[4][2], bfr[4][2];
#pragma unroll
        for (int m = 0; m < 4; ++m)
#pragma unroll
            for (int h = 0; h < 2; ++h) {
                int row = wr * 64 + m * 16 + l15;
                int sl = h * 4 + kb;
                afr[m][h] = *(const bf16x8*)&Asm[row * TBK + ((sl ^ (row & 7)) << 3)];
            }
#pragma unroll
        for (int n = 0; n < 4; ++n)
#pragma unroll
            for (int h = 0; h < 2; ++h) {
                int row = wc * 64 + n * 16 + l15;
                int sl = h * 4 + kb;
                bfr[n][h] = *(const bf16x8*)&Bsm[row * TBK + ((sl ^ (row & 7)) << 3)];
            }
#pragma unroll
        for (int m = 0; m < 4; ++m)
#pragma unroll
            for (int n = 0; n < 4; ++n) {
                acc[m][n] = __builtin_amdgcn_mfma_f32_16x16x32_bf16(afr[m][0], bfr[n][0], acc[m][n], 0, 0, 0);
                acc[m][n] = __builtin_amdgcn_mfma_f32_16x16x32_bf16(afr[m][1], bfr[n][1], acc[m][n], 0, 0, 0);
            }
        __syncthreads();
    }

    // C/D layout: col = lane&15, row = (lane>>4)*4 + reg  [m89-verified]
    const int orow0 = blockIdx.y * TBM + wr * 64;
    const long long ocol0 = qbase + wc * 64;
#pragma unroll
    for (int m = 0; m < 4; ++m)
#pragma unroll
        for (int n = 0; n < 4; ++n) {
            float* p = dist + (long long)(orow0 + m * 16 + kb * 4) * Q_ + ocol0 + n * 16 + l15;
#pragma unroll
            for (int r = 0; r < 4; ++r) p[(long long)r * Q_] = acc[m][n][r];
        }
}

// ---------------------------------------------------------------- fp32 fallback GEMM
__global__ __launch_bounds__(256) void gemm_kernel(const float* __restrict__ A,
                                                   const float* __restrict__ M,
                                                   float* __restrict__ dist,
                                                   int row0) {
    __shared__ float As[GBK][LDS_STRIDE];
    __shared__ float Bs[GBK][LDS_STRIDE];
    const int tid = threadIdx.x;
    const int tx = tid & 15;
    const int ty = tid >> 4;
    const long long qbase = (long long)blockIdx.x * GBN;
    const int arow = row0 + blockIdx.y * GBM;
    const int lr = tid >> 1;
    const int lk = (tid & 1) * 8;
    const float* Aptr = A + (long long)(arow + lr) * D_ + lk;
    const float* Mptr = M + (qbase + lr) * D_ + lk;
    float acc[8][8];
#pragma unroll
    for (int i = 0; i < 8; ++i)
#pragma unroll
        for (int j = 0; j < 8; ++j) acc[i][j] = 0.f;
    for (int kk = 0; kk < D_; kk += GBK) {
        float4 a0 = *(const float4*)(Aptr + kk);
        float4 a1 = *(const float4*)(Aptr + kk + 4);
        float4 b0 = *(const float4*)(Mptr + kk);
        float4 b1 = *(const float4*)(Mptr + kk + 4);
        As[lk + 0][lr] = a0.x; As[lk + 1][lr] = a0.y;
        As[lk + 2][lr] = a0.z; As[lk + 3][lr] = a0.w;
        As[lk + 4][lr] = a1.x; As[lk + 5][lr] = a1.y;
        As[lk + 6][lr] = a1.z; As[lk + 7][lr] = a1.w;
        Bs[lk + 0][lr] = b0.x; Bs[lk + 1][lr] = b0.y;
        Bs[lk + 2][lr] = b0.z; Bs[lk + 3][lr] = b0.w;
        Bs[lk + 4][lr] = b1.x; Bs[lk + 5][lr] = b1.y;
        Bs[lk + 6][lr] = b1.z; Bs[lk + 7][lr] = b1.w;
        __syncthreads();
#pragma unroll
        for (int k = 0; k < GBK; ++k) {
            float a[8], b[8];
            *(float4*)&a[0] = *(const float4*)&As[k][ty * 8];
            *(float4*)&a[4] = *(const float4*)&As[k][ty * 8 + 4];
            *(float4*)&b[0] = *(const float4*)&Bs[k][tx * 8];
            *(float4*)&b[4] = *(const float4*)&Bs[k][tx * 8 + 4];
#pragma unroll
            for (int i = 0; i < 8; ++i)
#pragma unroll
                for (int j = 0; j < 8; ++j) acc[i][j] = fmaf(a[i], b[j], acc[i][j]);
        }
        __syncthreads();
    }
    const int lrow0 = blockIdx.y * GBM + ty * 8;
    float* dbase = dist + (long long)lrow0 * Q_ + qbase + tx * 8;
#pragma unroll
    for (int i = 0; i < 8; ++i) {
        float4 w0 = make_float4(acc[i][0], acc[i][1], acc[i][2], acc[i][3]);
        float4 w1 = make_float4(acc[i][4], acc[i][5], acc[i][6], acc[i][7]);
        *(float4*)(dbase + (long long)i * Q_) = w0;
        *(float4*)(dbase + (long long)i * Q_ + 4) = w1;
    }
}

// ---------------------------------------------------------------- zero scratch
__global__ __launch_bounds__(256) void zero_kernel(unsigned* __restrict__ p, int n) {
    int i = blockIdx.x * 256 + threadIdx.x;
    if (i < n) p[i] = 0u;
}

// ---------------------------------------------------------------- per-(row,seg) histogram
__global__ __launch_bounds__(256) void hist_kernel(const float* __restrict__ dist,
                                                   unsigned* __restrict__ ghist) {
    __shared__ unsigned hist[4096];
    const int tid = threadIdx.x;
    const int row = blockIdx.x, seg = blockIdx.y;
    for (int i = tid; i < 4096; i += 256) hist[i] = 0u;
    __syncthreads();
    const float4* p = (const float4*)(dist + (long long)row * Q_ + (long long)seg * SEGSZ);
    for (int i = tid; i < SEGSZ / 4; i += 256) {
        float4 v = p[i];
        atomicAdd(&hist[key_of(v.x) >> 20], 1u);
        atomicAdd(&hist[key_of(v.y) >> 20], 1u);
        atomicAdd(&hist[key_of(v.z) >> 20], 1u);
        atomicAdd(&hist[key_of(v.w) >> 20], 1u);
    }
    __syncthreads();
    unsigned* gh = ghist + (long long)row * 4096;
    for (int i = tid; i < 4096; i += 256) {
        unsigned c = hist[i];
        if (c) atomicAdd(&gh[i], c);
    }
}

// ---------------------------------------------------------------- per-row threshold bin
__global__ __launch_bounds__(256) void thresh_kernel(const unsigned* __restrict__ ghist,
                                                     unsigned* __restrict__ thr) {
    __shared__ unsigned seg[256];
    __shared__ unsigned hloc[4096];
    const int tid = threadIdx.x;
    const unsigned* gh = ghist + (long long)blockIdx.x * 4096;
    unsigned s = 0;
    for (int j = 0; j < 16; ++j) {
        unsigned c = gh[tid * 16 + j];
        hloc[tid * 16 + j] = c;
        s += c;
    }
    seg[tid] = s;
    __syncthreads();
    if (tid == 0) {
        unsigned cum = 0; int bstar = 0;
        for (int sg = 255; sg >= 0; --sg) {
            if (cum + seg[sg] >= (unsigned)K_) {
                for (int b = sg * 16 + 15; ; --b) {
                    cum += hloc[b];
                    if (cum >= (unsigned)K_) { bstar = b; break; }
                }
                break;
            }
            cum += seg[sg];
        }
        thr[blockIdx.x] = (unsigned)bstar;
    }
}

// ---------------------------------------------------------------- per-(row,seg) filter+compact
__global__ __launch_bounds__(256) void filter_kernel(const float* __restrict__ dist,
                                                     const unsigned* __restrict__ thr,
                                                     unsigned* __restrict__ cnt,
                                                     float* __restrict__ candv,
                                                     unsigned* __restrict__ candi) {
    const int tid = threadIdx.x;
    const int row = blockIdx.x, seg = blockIdx.y;
    const unsigned bst = thr[row];
    const float4* p = (const float4*)(dist + (long long)row * Q_ + (long long)seg * SEGSZ);
    float* cv = candv + (long long)row * CAP;
    unsigned* ci = candi + (long long)row * CAP;
    const unsigned ibase = (unsigned)(seg * SEGSZ);
    for (int i = tid; i < SEGSZ / 4; i += 256) {
        float4 v = p[i];
        float a[4] = {v.x, v.y, v.z, v.w};
#pragma unroll
        for (int j = 0; j < 4; ++j) {
            if ((key_of(a[j]) >> 20) >= bst) {
                unsigned pidx = atomicAdd(&cnt[row], 1u);
                if (pidx < CAP) { cv[pidx] = a[j]; ci[pidx] = ibase + (unsigned)i * 4u + (unsigned)j; }
            }
        }
    }
}

// ---------------------------------------------------------------- per-row exact-K softmax + scatter
__global__ __launch_bounds__(256) void final_kernel(const unsigned* __restrict__ cnt,
                                                    const float* __restrict__ candv,
                                                    const unsigned* __restrict__ candi,
                                                    const int* __restrict__ labels,
                                                    float* __restrict__ out, int row0) {
    __shared__ float cval[CAP];
    __shared__ unsigned cidx[CAP];
    __shared__ float bins[C_];
    __shared__ float segf[256];
    __shared__ unsigned sh_tie, sh_tkey;
    __shared__ int sh_gstar;
    const int tid = threadIdx.x;
    const int row = blockIdx.x;
    unsigned c = cnt[row];
    const int n = (c < (unsigned)CAP) ? (int)c : CAP;
    for (int i = tid; i < n; i += 256) {
        cval[i] = candv[(long long)row * CAP + i];
        cidx[i] = candi[(long long)row * CAP + i];
    }
    for (int i = tid; i < C_; i += 256) bins[i] = 0.f;
    if (tid == 0) sh_tie = 0u;
    __syncthreads();

    float lm = -3.4e38f;
    for (int i = tid; i < n; i += 256) lm = fmaxf(lm, cval[i]);
    segf[tid] = lm;
    __syncthreads();
    for (int off = 128; off > 0; off >>= 1) {
        if (tid < off) segf[tid] = fmaxf(segf[tid], segf[tid + off]);
        __syncthreads();
    }
    const float m = segf[0];
    __syncthreads();

    for (int i = tid; i < n; i += 256) {
        unsigned ki = key_of(cval[i]);
        int g = 0, eq = 0;
        for (int j = 0; j < n; ++j) {
            unsigned kj = key_of(cval[j]);
            g += (kj > ki);
            eq += (kj == ki);
        }
        if (g < K_ && g + eq >= K_) { sh_tkey = ki; sh_gstar = g; }
    }
    __syncthreads();

    const unsigned tkey = sh_tkey;
    const int rem = K_ - sh_gstar;
    float part = 0.f;
    for (int i = tid; i < n; i += 256) {
        float v = cval[i];
        unsigned ki = key_of(v);
        float e = 0.f;
        if (ki > tkey) e = __expf((v - m) * INV_T);
        else if (ki == tkey) {
            if (atomicAdd(&sh_tie, 1u) < (unsigned)rem) e = __expf((v - m) * INV_T);
        }
        cval[i] = e;
        part += e;
    }
    segf[tid] = part;
    __syncthreads();
    for (int off = 128; off > 0; off >>= 1) {
        if (tid < off) segf[tid] += segf[tid + off];
        __syncthreads();
    }
    const float invS = 1.f / segf[0];

    for (int i = tid; i < n; i += 256) {
        float e = cval[i];
        if (e > 0.f) {
            int lbl = labels[cidx[i]];
            if ((unsigned)lbl < (unsigned)C_) atomicAdd(&bins[lbl], e);
        }
    }
    __syncthreads();

    const long long ob = (long long)(row0 + row) * C_;
    for (int i = tid; i < C_; i += 256)
        out[ob + i] = fminf(bins[i] * invS + EPS_, 1.0f);
}

// ---------------------------------------------------------------- launch
extern "C" void kernel_launch(void* const* d_in, const int* in_sizes, int n_in,
                              void* d_out, int out_size, void* d_ws, size_t ws_size,
                              hipStream_t stream) {
    const float* x = (const float*)d_in[0];
    const float* mem = (const float*)d_in[1];
    const int* lab = (const int*)d_in[2];
    float* out = (float*)d_out;

    const size_t distpr = (size_t)Q_ * 4;
    const size_t selpr = 4096 * 4 + 8 + (size_t)CAP * 8;  // ghist + cnt + thr + cands

    // ---- MFMA path workspace head: xn + Ahi/Alo + Bhi/Blo
    const size_t headM = (size_t)B_ * D_ * 4 + (size_t)B_ * D_ * 2 * 2 + (size_t)Q_ * D_ * 2 * 2;
    int R = 0;
    for (int r = 1024; r >= 128; r >>= 1)
        if (headM + (size_t)r * (distpr + selpr) <= ws_size) { R = r; break; }

    if (R) {
        float* xn = (float*)d_ws;
        unsigned short* Ahi = (unsigned short*)(xn + (size_t)B_ * D_);
        unsigned short* Alo = Ahi + (size_t)B_ * D_;
        unsigned short* Bhi = Alo + (size_t)B_ * D_;
        unsigned short* Blo = Bhi + (size_t)Q_ * D_;
        float* dist = (float*)(Blo + (size_t)Q_ * D_);
        unsigned* ghist = (unsigned*)(dist + (size_t)R * Q_);
        unsigned* cnt = ghist + (size_t)R * 4096;
        unsigned* thr = cnt + R;
        float* candv = (float*)(thr + R);
        unsigned* candi = (unsigned*)(candv + (size_t)R * CAP);
        const int zero_n = R * 4096 + R;

        normsplit_kernel<<<B_, 256, 0, stream>>>(x, Ahi, Alo);
        convB_kernel<<<4096, 256, 0, stream>>>(mem, Bhi, Blo);
        for (int r0 = 0; r0 < B_; r0 += R) {
            dim3 g(Q_ / TBN, R / TBM);
            mfma_gemm<<<g, 256, 0, stream>>>(Ahi, Alo, Bhi, Blo, dist, r0);
            zero_kernel<<<(zero_n + 255) / 256, 256, 0, stream>>>(ghist, zero_n);
            dim3 hs(R, SEGS);
            hist_kernel<<<hs, 256, 0, stream>>>(dist, ghist);
            thresh_kernel<<<R, 256, 0, stream>>>(ghist, thr);
            filter_kernel<<<hs, 256, 0, stream>>>(dist, thr, cnt, candv, candi);
            final_kernel<<<R, 256, 0, stream>>>(cnt, candv, candi, lab, out, r0);
        }
        return;
    }

    // ---- fallback: fp32 vector GEMM (round-2 path)
    float* xn = (float*)d_ws;
    const size_t fixed = (size_t)B_ * D_ * sizeof(float);
    const size_t per_row = distpr + selpr;
    int Rf = 1024;
    while (Rf > 32 && fixed + (size_t)Rf * per_row > ws_size) Rf >>= 1;

    float* dist = xn + (size_t)B_ * D_;
    unsigned* ghist = (unsigned*)(dist + (size_t)Rf * Q_);
    unsigned* cnt = ghist + (size_t)Rf * 4096;
    unsigned* thr = cnt + Rf;
    float* candv = (float*)(thr + Rf);
    unsigned* candi = (unsigned*)(candv + (size_t)Rf * CAP);
    const int zero_n = Rf * 4096 + Rf;

    norm_kernel<<<B_, 256, 0, stream>>>(x, xn);
    for (int r0 = 0; r0 < B_; r0 += Rf) {
        dim3 g(Q_ / GBN, Rf / GBM);
        gemm_kernel<<<g, 256, 0, stream>>>(xn, mem, dist, r0);
        zero_kernel<<<(zero_n + 255) / 256, 256, 0, stream>>>(ghist, zero_n);
        dim3 hs(Rf, SEGS);
        hist_kernel<<<hs, 256, 0, stream>>>(dist, ghist);
        thresh_kernel<<<Rf, 256, 0, stream>>>(ghist, thr);
        filter_kernel<<<hs, 256, 0, stream>>>(dist, thr, cnt, candv, candi);
        final_kernel<<<Rf, 256, 0, stream>>>(cnt, candv, candi, lab, out, r0);
    }
}